// Round 1
// baseline (475.919 us; speedup 1.0000x reference)
//
#include <hip/hip_runtime.h>
#include <math.h>

// Problem constants
#define B_   32
#define H_   512
#define W_   512
#define C_   3
#define M_   96          // B_*C_
#define NW_  263         // floor((512+15)/2)
#define NH_  263
#define DETPER 69169     // 263*263
#define DETTOT 207507    // 3*DETPER
#define DETSTRIDE 207508 // padded to multiple of 4 for float4 alignment
#define NVEC 51876       // DETTOT/4 (floor); tail = 3 elements
#define KRANK  103753u   // (DETTOT-1)/2, 0-based median rank

#define SXS 148          // sX row stride (floats): mult of 4 (16B align), 37 odd -> b128 banks spread
#define SLS 68           // sLO/sHI row stride: mult of 4; col reads (4*row+tx)%32 conflict-free

// db8 reconstruction filters (pre-derived; dec filters are reversed versions,
// and the reference's conv reduces to: ca[j] = sum_k xe[2j+k]*rec_lo[k])
__device__ __constant__ float RLO[16] = {
    0.05441584224308161f,  0.3128715909144659f,   0.6756307362980128f,
    0.5853546836548691f,  -0.015829105256023893f, -0.2840155429624281f,
    0.00047248457399797254f, 0.128747426620186f,  -0.01736930100202211f,
   -0.04408825393106472f,  0.013981027917015516f,  0.008746094047015655f,
   -0.00487035299301066f, -0.0003917403729959771f, 0.0006754494059985568f,
   -0.00011747678400228192f};
__device__ __constant__ float RHI[16] = {
   -0.00011747678400228192f, -0.0006754494059985568f, -0.0003917403729959771f,
    0.00487035299301066f,     0.008746094047015655f,  -0.013981027917015516f,
   -0.04408825393106472f,     0.01736930100202211f,    0.128747426620186f,
   -0.00047248457399797254f, -0.2840155429624281f,     0.015829105256023893f,
    0.5853546836548691f,     -0.6756307362980128f,     0.3128715909144659f,
   -0.05441584224308161f};

// Symmetric reflection of padded index q into [0, N)
__device__ __forceinline__ int refl(int q, int N) {
    if (q < 0)  return -q - 1;
    if (q >= N) return 2 * N - 1 - q;
    return q;
}

__device__ __forceinline__ float softthr(float v, float thr) {
    float a = fabsf(v) - thr;
    return a > 0.f ? copysignf(a, v) : 0.f;
}

// -------- zero-init for histogram region (no hipMemsetAsync in capture) --------
__global__ __launch_bounds__(256) void k_zero(unsigned* __restrict__ p, int n) {
    int i = blockIdx.x * 256 + threadIdx.x;
    if (i < n) p[i] = 0u;
}

// ---------------- Fused forward: row DWT + column DWT ----------------
// One block per (m, 64-jw tile, 16-jh tile). Stages 46 x-rows x 142 x-cols of one
// channel, row-DWTs them to 46x64 lo/hi, col-DWTs to ll/det.
// v2: register-blocked (4 outputs/thread) + b128 LDS reads, conflict-aware strides.
__global__ __launch_bounds__(256) void k_fwd(const float* __restrict__ x,
                                             float* __restrict__ ll,
                                             float* __restrict__ det) {
    __shared__ float sX[46 * SXS];               // 27.2 KB
    __shared__ float sLO[46 * SLS], sHI[46 * SLS]; // 12.5 KB each; total 52.3 KB -> 3 blk/CU
    const int m   = blockIdx.x;                  // channels adjacent in dispatch
    const int jw0 = blockIdx.y * 64;             // 5 tiles
    const int jh0 = blockIdx.z * 16;             // 17 tiles
    const int b = m / 3, c = m - 3 * (m / 3);
    const int tid = threadIdx.x;
    const int prow0 = 2 * jh0 - 14, pcol0 = 2 * jw0 - 14;
    // stage x tile (channel c), symmetric-reflected at borders
    for (int l = tid; l < 46 * 142; l += 256) {
        int rr = l / 142, cl = l - rr * 142;
        int h = refl(prow0 + rr, H_);
        int w = refl(pcol0 + cl, W_);
        sX[rr * SXS + cl] = x[((size_t)(b * H_ + h) * W_ + w) * C_ + c];
    }
    __syncthreads();
    // row DWT: thread computes j = 4q..4q+3 for rows rbase, rbase+16, rbase+32.
    // Reads 6 x b128 (24 floats; last 2 unused) per row; writes float4 lo + float4 hi.
    {
        const int q = (tid >> 2) & 15;
        const int rbase = (tid & 3) + 4 * (tid >> 6);   // 0..15
        auto rowdwt = [&](int rr) {
            const float4* p4 = (const float4*)&sX[rr * SXS + 8 * q];  // 16B aligned
            float4 f0 = p4[0], f1 = p4[1], f2 = p4[2], f3 = p4[3], f4v = p4[4], f5 = p4[5];
            float v[24] = {f0.x,f0.y,f0.z,f0.w, f1.x,f1.y,f1.z,f1.w,
                           f2.x,f2.y,f2.z,f2.w, f3.x,f3.y,f3.z,f3.w,
                           f4v.x,f4v.y,f4v.z,f4v.w, f5.x,f5.y,f5.z,f5.w};
            float lo0=0.f,lo1=0.f,lo2=0.f,lo3=0.f, hi0=0.f,hi1=0.f,hi2=0.f,hi3=0.f;
#pragma unroll
            for (int k = 0; k < 16; ++k) {
                float w0 = RLO[k], w1 = RHI[k];
                lo0 = fmaf(v[k],     w0, lo0);  hi0 = fmaf(v[k],     w1, hi0);
                lo1 = fmaf(v[k + 2], w0, lo1);  hi1 = fmaf(v[k + 2], w1, hi1);
                lo2 = fmaf(v[k + 4], w0, lo2);  hi2 = fmaf(v[k + 4], w1, hi2);
                lo3 = fmaf(v[k + 6], w0, lo3);  hi3 = fmaf(v[k + 6], w1, hi3);
            }
            *(float4*)&sLO[rr * SLS + 4 * q] = make_float4(lo0, lo1, lo2, lo3);
            *(float4*)&sHI[rr * SLS + 4 * q] = make_float4(hi0, hi1, hi2, hi3);
        };
        rowdwt(rbase);
        rowdwt(rbase + 16);
        if (rbase + 32 < 46) rowdwt(rbase + 32);
    }
    __syncthreads();
    // column DWT: thread computes 4 consecutive jh (dy = 4*tg+d) at col tx,
    // loading the shared 22-row window once into registers.
    const int tx = tid & 63, tg = tid >> 6;
    const int jw = jw0 + tx;
    if (jw >= NW_) return;
    float vl[22], vh[22];
#pragma unroll
    for (int s = 0; s < 22; ++s) {
        int row = 8 * tg + s;                    // <= 45
        vl[s] = sLO[row * SLS + tx];
        vh[s] = sHI[row * SLS + tx];
    }
    float* llp = ll + (size_t)m * DETPER;
    float* dp  = det + (size_t)m * DETSTRIDE;
#pragma unroll
    for (int d = 0; d < 4; ++d) {
        int jh = jh0 + 4 * tg + d;
        if (jh >= NH_) continue;
        float a0 = 0.f, a1 = 0.f, a2 = 0.f, a3 = 0.f;
#pragma unroll
        for (int k = 0; k < 16; ++k) {
            float fl = vl[2 * d + k], fh = vh[2 * d + k];
            a0 = fmaf(fl, RLO[k], a0);
            a1 = fmaf(fl, RHI[k], a1);
            a2 = fmaf(fh, RLO[k], a2);
            a3 = fmaf(fh, RHI[k], a3);
        }
        size_t o = (size_t)jh * NW_ + jw;
        llp[o] = a0;                             // LL
        dp[o] = a1;                              // LH
        dp[DETPER + o] = a2;                     // HL
        dp[2 * DETPER + o] = a3;                 // HH
    }
}

// ---------------- Median: 3-pass radix histogram refinement over det ----------
__global__ __launch_bounds__(256) void k_hist1(const float* __restrict__ det,
                                               unsigned* __restrict__ hist) {
    __shared__ unsigned h[2048];
    const int tid = threadIdx.x, m = blockIdx.x;
    for (int i = tid; i < 2048; i += 256) h[i] = 0u;
    __syncthreads();
    const float* dp = det + (size_t)m * DETSTRIDE;
    const float4* dp4 = (const float4*)dp;
    const int stride = gridDim.y * 256;
    for (int v = blockIdx.y * 256 + tid; v < NVEC; v += stride) {
        float4 f = dp4[v];
        atomicAdd(&h[__float_as_uint(fabsf(f.x)) >> 21], 1u);
        atomicAdd(&h[__float_as_uint(fabsf(f.y)) >> 21], 1u);
        atomicAdd(&h[__float_as_uint(fabsf(f.z)) >> 21], 1u);
        atomicAdd(&h[__float_as_uint(fabsf(f.w)) >> 21], 1u);
    }
    if (blockIdx.y == 0 && tid < DETTOT - 4 * NVEC) {
        unsigned u = __float_as_uint(fabsf(dp[4 * NVEC + tid]));
        atomicAdd(&h[u >> 21], 1u);
    }
    __syncthreads();
    for (int i = tid; i < 2048; i += 256)
        if (h[i]) atomicAdd(&hist[m * 2048 + i], h[i]);
}

__global__ __launch_bounds__(256) void k_hist2(const float* __restrict__ det,
                                               const int* __restrict__ selBin1,
                                               unsigned* __restrict__ hist) {
    __shared__ unsigned h[2048];
    const int tid = threadIdx.x, m = blockIdx.x;
    const unsigned target = (unsigned)selBin1[m];
    for (int i = tid; i < 2048; i += 256) h[i] = 0u;
    __syncthreads();
    const float* dp = det + (size_t)m * DETSTRIDE;
    const float4* dp4 = (const float4*)dp;
    const int stride = gridDim.y * 256;
    for (int v = blockIdx.y * 256 + tid; v < NVEC; v += stride) {
        float4 f = dp4[v];
        unsigned a = __float_as_uint(fabsf(f.x));
        unsigned b = __float_as_uint(fabsf(f.y));
        unsigned c = __float_as_uint(fabsf(f.z));
        unsigned d = __float_as_uint(fabsf(f.w));
        if ((a >> 21) == target) atomicAdd(&h[(a >> 10) & 0x7FFu], 1u);
        if ((b >> 21) == target) atomicAdd(&h[(b >> 10) & 0x7FFu], 1u);
        if ((c >> 21) == target) atomicAdd(&h[(c >> 10) & 0x7FFu], 1u);
        if ((d >> 21) == target) atomicAdd(&h[(d >> 10) & 0x7FFu], 1u);
    }
    if (blockIdx.y == 0 && tid < DETTOT - 4 * NVEC) {
        unsigned u = __float_as_uint(fabsf(dp[4 * NVEC + tid]));
        if ((u >> 21) == target) atomicAdd(&h[(u >> 10) & 0x7FFu], 1u);
    }
    __syncthreads();
    for (int i = tid; i < 2048; i += 256)
        if (h[i]) atomicAdd(&hist[m * 2048 + i], h[i]);
}

__global__ __launch_bounds__(256) void k_hist3(const float* __restrict__ det,
                                               const int* __restrict__ selBin1,
                                               const int* __restrict__ selBin2,
                                               unsigned* __restrict__ hist) {
    __shared__ unsigned h[1024];
    const int tid = threadIdx.x, m = blockIdx.x;
    const unsigned target = ((unsigned)selBin1[m] << 11) | (unsigned)selBin2[m];
    for (int i = tid; i < 1024; i += 256) h[i] = 0u;
    __syncthreads();
    const float* dp = det + (size_t)m * DETSTRIDE;
    const float4* dp4 = (const float4*)dp;
    const int stride = gridDim.y * 256;
    for (int v = blockIdx.y * 256 + tid; v < NVEC; v += stride) {
        float4 f = dp4[v];
        unsigned a = __float_as_uint(fabsf(f.x));
        unsigned b = __float_as_uint(fabsf(f.y));
        unsigned c = __float_as_uint(fabsf(f.z));
        unsigned d = __float_as_uint(fabsf(f.w));
        if ((a >> 10) == target) atomicAdd(&h[a & 0x3FFu], 1u);
        if ((b >> 10) == target) atomicAdd(&h[b & 0x3FFu], 1u);
        if ((c >> 10) == target) atomicAdd(&h[c & 0x3FFu], 1u);
        if ((d >> 10) == target) atomicAdd(&h[d & 0x3FFu], 1u);
    }
    if (blockIdx.y == 0 && tid < DETTOT - 4 * NVEC) {
        unsigned u = __float_as_uint(fabsf(dp[4 * NVEC + tid]));
        if ((u >> 10) == target) atomicAdd(&h[u & 0x3FFu], 1u);
    }
    __syncthreads();
    for (int i = tid; i < 1024; i += 256)
        if (h[i]) atomicAdd(&hist[m * 1024 + i], h[i]);
}

// Cooperative select: find bin of LDS histogram (nb multiple of 256) containing `rank`
__device__ int histSelect(unsigned* hist, int nb, unsigned rank, unsigned* rem) {
    __shared__ unsigned ps[256];
    __shared__ int s_bin;
    __shared__ unsigned s_rem;
    const int tid = threadIdx.x;
    if (tid == 0) { s_bin = 0; s_rem = 0; }      // deterministic fallback
    const int per = nb >> 8;
    unsigned s = 0;
    for (int i = 0; i < per; ++i) s += hist[tid * per + i];
    ps[tid] = s;
    __syncthreads();
    for (int off = 1; off < 256; off <<= 1) {
        unsigned v = ps[tid];
        unsigned add = (tid >= off) ? ps[tid - off] : 0u;
        __syncthreads();
        ps[tid] = v + add;
        __syncthreads();
    }
    unsigned incl = ps[tid], excl = incl - s;
    if (rank >= excl && rank < incl) {
        unsigned cum = excl;
        for (int i = 0; i < per; ++i) {
            unsigned c = hist[tid * per + i];
            if (cum + c > rank) { s_bin = tid * per + i; s_rem = rank - cum; break; }
            cum += c;
        }
    }
    __syncthreads();
    int rbin = s_bin;
    unsigned rr = s_rem;
    __syncthreads();   // protect shared reuse across calls
    *rem = rr;
    return rbin;
}

__global__ __launch_bounds__(256) void k_sel2048(const unsigned* __restrict__ hist,
                                                 const unsigned* __restrict__ rankIn, // null => KRANK
                                                 int* __restrict__ selBin,
                                                 unsigned* __restrict__ rankOut) {
    __shared__ unsigned h[2048];
    const int m = blockIdx.x, tid = threadIdx.x;
    for (int i = tid; i < 2048; i += 256) h[i] = hist[m * 2048 + i];
    __syncthreads();
    unsigned rank = rankIn ? rankIn[m] : KRANK;
    unsigned rem;
    int bin = histSelect(h, 2048, rank, &rem);
    if (tid == 0) { selBin[m] = bin; rankOut[m] = rem; }
}

__global__ __launch_bounds__(256) void k_sel3(const unsigned* __restrict__ hist,
                                              const unsigned* __restrict__ rankIn,
                                              const int* __restrict__ selBin1,
                                              const int* __restrict__ selBin2,
                                              float* __restrict__ tval) {
    __shared__ unsigned h[1024];
    const int m = blockIdx.x, tid = threadIdx.x;
    for (int i = tid; i < 1024; i += 256) h[i] = hist[m * 1024 + i];
    __syncthreads();
    unsigned rem;
    int low = histSelect(h, 1024, rankIn[m], &rem);
    if (tid == 0) {
        unsigned bits = ((unsigned)selBin1[m] << 21) | ((unsigned)selBin2[m] << 10) | (unsigned)low;
        double med = (double)__uint_as_float(bits);
        // t = median/0.6745 * sqrt(2*ln(512*512))
        tval[m] = (float)(med / 0.6745 * 4.995327667046959);
    }
}

// ---------------- Fused inverse: soft-threshold + column IDWT + row IDWT ------
// One block per (m, 64-w tile, 32-t tile). Stages 23x39 of 4 subbands (thresholded),
// computes 32x39 rl/rh in LDS, then row-IDWT to a 32x64 output tile (NHWC).
// v2: register-blocked — col-IDWT does 4 consecutive tr per thread sharing a 9-row
// window; row-IDWT does 8 consecutive wloc per thread from 6 x ds_read_b128.
__global__ __launch_bounds__(256) void k_inv(const float* __restrict__ ll,
                                             const float* __restrict__ det,
                                             const float* __restrict__ tval,
                                             float* __restrict__ out) {
    __shared__ float sLL[23 * 40], sLH[23 * 40], sHL[23 * 40], sHH[23 * 40];
    __shared__ float sRL[32 * 40], sRH[32 * 40];
    const int m  = blockIdx.x;                   // channels adjacent in dispatch
    const int w0 = blockIdx.y * 64;              // 8 tiles
    const int t0 = blockIdx.z * 32;              // 16 tiles
    const int b = m / 3, c = m - 3 * (m / 3);
    const int tid = threadIdx.x;
    const float thr = tval[m];
    const int jW0 = w0 >> 1, s0 = t0 >> 1;
    const float* llp = ll + (size_t)m * DETPER;
    const float* dp  = det + (size_t)m * DETSTRIDE;
    for (int l = tid; l < 23 * 39; l += 256) {
        int rr = l / 39, cc = l - rr * 39;
        size_t o = (size_t)(s0 + rr) * NW_ + (jW0 + cc);
        int li = rr * 40 + cc;
        sLL[li] = llp[o];
        sLH[li] = softthr(dp[o], thr);
        sHL[li] = softthr(dp[DETPER + o], thr);
        sHH[li] = softthr(dp[2 * DETPER + o], thr);
    }
    __syncthreads();
    // column IDWT: item (tg 0..7, cc 0..38): 4 consecutive tr = 4*tg+d share a
    // 9-row x 4-subband window (36 b32 reads for 8 outputs).
    for (int l = tid; l < 8 * 39; l += 256) {
        int tg = l / 39, cc = l - tg * 39;
        float l9[9], d9[9], g9[9], h9[9];
#pragma unroll
        for (int s = 0; s < 9; ++s) {
            int li = (2 * tg + s) * 40 + cc;     // rows 2tg..2tg+8 <= 22
            l9[s] = sLL[li]; d9[s] = sLH[li]; g9[s] = sHL[li]; h9[s] = sHH[li];
        }
#pragma unroll
        for (int d = 0; d < 4; ++d) {
            int sl = d >> 1, r = d & 1;
            float aL = 0.f, aH = 0.f;
#pragma unroll
            for (int a = 0; a < 8; ++a) {
                int s = sl + 7 - a;              // in [sl, sl+7] subset of [0,8]
                float wl = RLO[2 * a + r], wh = RHI[2 * a + r];
                aL = fmaf(l9[s], wl, fmaf(d9[s], wh, aL));
                aH = fmaf(g9[s], wl, fmaf(h9[s], wh, aH));
            }
            sRL[(4 * tg + d) * 40 + cc] = aL;
            sRH[(4 * tg + d) * 40 + cc] = aH;
        }
    }
    __syncthreads();
    // row IDWT + NHWC store: thread (tr = tid>>3, jg = tid&7) produces the 8
    // outputs wloc = 8jg..8jg+7 from words [4jg, 4jg+10] of sRL/sRH (3 b128 each).
    {
        const int tr = tid >> 3, jg = tid & 7;
        const float4* pl = (const float4*)&sRL[tr * 40 + 4 * jg];  // 16B aligned
        const float4* ph = (const float4*)&sRH[tr * 40 + 4 * jg];
        float4 L0 = pl[0], L1 = pl[1], L2 = pl[2];
        float4 K0 = ph[0], K1 = ph[1], K2 = ph[2];
        float rl[12] = {L0.x,L0.y,L0.z,L0.w, L1.x,L1.y,L1.z,L1.w, L2.x,L2.y,L2.z,L2.w};
        float rh[12] = {K0.x,K0.y,K0.z,K0.w, K1.x,K1.y,K1.z,K1.w, K2.x,K2.y,K2.z,K2.w};
        size_t obase = ((size_t)(b * H_ + (t0 + tr)) * W_ + (w0 + 8 * jg)) * C_ + c;
#pragma unroll
        for (int u = 0; u < 4; ++u) {
#pragma unroll
            for (int r = 0; r < 2; ++r) {
                float acc = 0.f;
#pragma unroll
                for (int a = 0; a < 8; ++a) {
                    int s = u + 7 - a;           // in [u, u+7] subset of [0,10]
                    acc = fmaf(rl[s], RLO[2 * a + r], fmaf(rh[s], RHI[2 * a + r], acc));
                }
                out[obase + (size_t)(2 * u + r) * C_] = acc;
            }
        }
    }
}

extern "C" void kernel_launch(void* const* d_in, const int* in_sizes, int n_in,
                              void* d_out, int out_size, void* d_ws, size_t ws_size,
                              hipStream_t stream) {
    const float* x = (const float*)d_in[0];
    float* out = (float*)d_out;

    char* ws = (char*)d_ws;
    float* ll  = (float*)ws; ws += (size_t)M_ * DETPER * 4;     // 26.56 MB
    float* det = (float*)ws; ws += (size_t)M_ * DETSTRIDE * 4;  // 79.68 MB  [m][{lh,hl,hh}][DETPER]
    unsigned* hist1 = (unsigned*)ws; ws += (size_t)M_ * 2048 * 4;
    unsigned* hist2 = (unsigned*)ws; ws += (size_t)M_ * 2048 * 4;
    unsigned* hist3 = (unsigned*)ws; ws += (size_t)M_ * 1024 * 4;
    int*      selBin1 = (int*)ws;      ws += M_ * 4;
    int*      selBin2 = (int*)ws;      ws += M_ * 4;
    unsigned* rank1   = (unsigned*)ws; ws += M_ * 4;
    unsigned* rank2   = (unsigned*)ws; ws += M_ * 4;
    float*    tval    = (float*)ws;    ws += M_ * 4;
    // total ws usage: ~108.2 MB

    const int histWords = M_ * (2048 + 2048 + 1024);            // 491,520
    k_zero   <<<dim3((histWords + 255) / 256), 256, 0, stream>>>(hist1, histWords);
    k_fwd    <<<dim3(M_, 5, 17),  256, 0, stream>>>(x, ll, det);
    k_hist1  <<<dim3(M_, 16),     256, 0, stream>>>(det, hist1);
    k_sel2048<<<dim3(M_),         256, 0, stream>>>(hist1, nullptr, selBin1, rank1);
    k_hist2  <<<dim3(M_, 16),     256, 0, stream>>>(det, selBin1, hist2);
    k_sel2048<<<dim3(M_),         256, 0, stream>>>(hist2, rank1, selBin2, rank2);
    k_hist3  <<<dim3(M_, 16),     256, 0, stream>>>(det, selBin1, selBin2, hist3);
    k_sel3   <<<dim3(M_),         256, 0, stream>>>(hist3, rank2, selBin1, selBin2, tval);
    k_inv    <<<dim3(M_, 8, 16),  256, 0, stream>>>(ll, det, tval, out);
}

// Round 2
// 435.747 us; speedup vs baseline: 1.0922x; 1.0922x over previous
//
#include <hip/hip_runtime.h>
#include <math.h>

// Problem constants
#define B_   32
#define H_   512
#define W_   512
#define C_   3
#define M_   96          // B_*C_
#define NW_  263         // floor((512+15)/2)
#define NH_  263
#define DETPER 69169     // 263*263
#define DETTOT 207507    // 3*DETPER
#define DETSTRIDE 207508 // padded to multiple of 4 for float4 alignment
#define NVEC 51876       // DETTOT/4 (floor); tail = 3 elements
#define KRANK  103753u   // (DETTOT-1)/2, 0-based median rank

#define SXS 144          // sX row stride (floats)
#define CR  12           // sX chunk rows (46 = 12+12+12+10)

// db8 reconstruction filters (pre-derived; dec filters are reversed versions,
// and the reference's conv reduces to: ca[j] = sum_k xe[2j+k]*rec_lo[k])
__device__ __constant__ float RLO[16] = {
    0.05441584224308161f,  0.3128715909144659f,   0.6756307362980128f,
    0.5853546836548691f,  -0.015829105256023893f, -0.2840155429624281f,
    0.00047248457399797254f, 0.128747426620186f,  -0.01736930100202211f,
   -0.04408825393106472f,  0.013981027917015516f,  0.008746094047015655f,
   -0.00487035299301066f, -0.0003917403729959771f, 0.0006754494059985568f,
   -0.00011747678400228192f};
__device__ __constant__ float RHI[16] = {
   -0.00011747678400228192f, -0.0006754494059985568f, -0.0003917403729959771f,
    0.00487035299301066f,     0.008746094047015655f,  -0.013981027917015516f,
   -0.04408825393106472f,     0.01736930100202211f,    0.128747426620186f,
   -0.00047248457399797254f, -0.2840155429624281f,     0.015829105256023893f,
    0.5853546836548691f,     -0.6756307362980128f,     0.3128715909144659f,
   -0.05441584224308161f};

// Symmetric reflection of padded index q into [0, N)
__device__ __forceinline__ int refl(int q, int N) {
    if (q < 0)  return -q - 1;
    if (q >= N) return 2 * N - 1 - q;
    return q;
}

__device__ __forceinline__ float softthr(float v, float thr) {
    float a = fabsf(v) - thr;
    return a > 0.f ? copysignf(a, v) : 0.f;
}

// -------- zero-init for histogram region (no hipMemsetAsync in capture) --------
__global__ __launch_bounds__(256) void k_zero(unsigned* __restrict__ p, int n) {
    int i = blockIdx.x * 256 + threadIdx.x;
    if (i < n) p[i] = 0u;
}

// ---------------- Fused forward: row DWT + column DWT ----------------
// One block per (m, 64-jw tile, 16-jh tile). v3: x-tile staged in 4 chunks of <=12
// rows through a small reused LDS buffer (29.8 KB total -> 5 blocks/CU instead of 3).
// Row-DWT uses round-0 conflict-free stride-8B reads; col-DWT keeps the
// register-window form (22 rows loaded once, 4 jh outputs per thread).
__global__ __launch_bounds__(256) void k_fwd(const float* __restrict__ x,
                                             float* __restrict__ ll,
                                             float* __restrict__ det) {
    __shared__ float sX[CR * SXS];                 // 6.75 KB, reused 4x
    __shared__ float sLO[46 * 64], sHI[46 * 64];   // 11.5 KB each
    const int m   = blockIdx.x;                    // channels adjacent in dispatch
    const int jw0 = blockIdx.y * 64;               // 5 tiles
    const int jh0 = blockIdx.z * 16;               // 17 tiles
    const int b = m / 3, c = m - 3 * (m / 3);
    const int tid = threadIdx.x;
    const int prow0 = 2 * jh0 - 14, pcol0 = 2 * jw0 - 14;
    // chunked: stage CR padded-rows, row-DWT them, repeat (sX reused)
    for (int r0 = 0; r0 < 46; r0 += CR) {
        const int nr = (46 - r0) < CR ? (46 - r0) : CR;
        for (int l = tid; l < nr * 142; l += 256) {
            int rr = l / 142, cl = l - rr * 142;
            int h = refl(prow0 + r0 + rr, H_);
            int w = refl(pcol0 + cl, W_);
            sX[rr * SXS + cl] = x[((size_t)(b * H_ + h) * W_ + w) * C_ + c];
        }
        __syncthreads();
        for (int l = tid; l < nr * 64; l += 256) {
            int rr = l >> 6, j = l & 63;
            const float* px = &sX[rr * SXS + 2 * j];
            float al = 0.f, ah = 0.f;
#pragma unroll
            for (int k = 0; k < 16; ++k) {
                al = fmaf(px[k], RLO[k], al);
                ah = fmaf(px[k], RHI[k], ah);
            }
            sLO[(r0 + rr) * 64 + j] = al;
            sHI[(r0 + rr) * 64 + j] = ah;
        }
        __syncthreads();                           // sX reused next chunk
    }
    // column DWT: thread computes 4 consecutive jh (dy = 4*tg+d) at col tx,
    // loading the shared 22-row window once into registers.
    const int tx = tid & 63, tg = tid >> 6;
    const int jw = jw0 + tx;
    if (jw >= NW_) return;
    float vl[22], vh[22];
#pragma unroll
    for (int s = 0; s < 22; ++s) {
        int row = 8 * tg + s;                      // <= 45
        vl[s] = sLO[row * 64 + tx];
        vh[s] = sHI[row * 64 + tx];
    }
    float* llp = ll + (size_t)m * DETPER;
    float* dp  = det + (size_t)m * DETSTRIDE;
#pragma unroll
    for (int d = 0; d < 4; ++d) {
        int jh = jh0 + 4 * tg + d;
        if (jh >= NH_) continue;
        float a0 = 0.f, a1 = 0.f, a2 = 0.f, a3 = 0.f;
#pragma unroll
        for (int k = 0; k < 16; ++k) {
            float fl = vl[2 * d + k], fh = vh[2 * d + k];
            a0 = fmaf(fl, RLO[k], a0);
            a1 = fmaf(fl, RHI[k], a1);
            a2 = fmaf(fh, RLO[k], a2);
            a3 = fmaf(fh, RHI[k], a3);
        }
        size_t o = (size_t)jh * NW_ + jw;
        llp[o] = a0;                               // LL
        dp[o] = a1;                                // LH
        dp[DETPER + o] = a2;                       // HL
        dp[2 * DETPER + o] = a3;                   // HH
    }
}

// ---------------- Median: 3-pass radix histogram refinement over det ----------
__global__ __launch_bounds__(256) void k_hist1(const float* __restrict__ det,
                                               unsigned* __restrict__ hist) {
    __shared__ unsigned h[2048];
    const int tid = threadIdx.x, m = blockIdx.x;
    for (int i = tid; i < 2048; i += 256) h[i] = 0u;
    __syncthreads();
    const float* dp = det + (size_t)m * DETSTRIDE;
    const float4* dp4 = (const float4*)dp;
    const int stride = gridDim.y * 256;
    for (int v = blockIdx.y * 256 + tid; v < NVEC; v += stride) {
        float4 f = dp4[v];
        atomicAdd(&h[__float_as_uint(fabsf(f.x)) >> 21], 1u);
        atomicAdd(&h[__float_as_uint(fabsf(f.y)) >> 21], 1u);
        atomicAdd(&h[__float_as_uint(fabsf(f.z)) >> 21], 1u);
        atomicAdd(&h[__float_as_uint(fabsf(f.w)) >> 21], 1u);
    }
    if (blockIdx.y == 0 && tid < DETTOT - 4 * NVEC) {
        unsigned u = __float_as_uint(fabsf(dp[4 * NVEC + tid]));
        atomicAdd(&h[u >> 21], 1u);
    }
    __syncthreads();
    for (int i = tid; i < 2048; i += 256)
        if (h[i]) atomicAdd(&hist[m * 2048 + i], h[i]);
}

__global__ __launch_bounds__(256) void k_hist2(const float* __restrict__ det,
                                               const int* __restrict__ selBin1,
                                               unsigned* __restrict__ hist) {
    __shared__ unsigned h[2048];
    const int tid = threadIdx.x, m = blockIdx.x;
    const unsigned target = (unsigned)selBin1[m];
    for (int i = tid; i < 2048; i += 256) h[i] = 0u;
    __syncthreads();
    const float* dp = det + (size_t)m * DETSTRIDE;
    const float4* dp4 = (const float4*)dp;
    const int stride = gridDim.y * 256;
    for (int v = blockIdx.y * 256 + tid; v < NVEC; v += stride) {
        float4 f = dp4[v];
        unsigned a = __float_as_uint(fabsf(f.x));
        unsigned b = __float_as_uint(fabsf(f.y));
        unsigned c = __float_as_uint(fabsf(f.z));
        unsigned d = __float_as_uint(fabsf(f.w));
        if ((a >> 21) == target) atomicAdd(&h[(a >> 10) & 0x7FFu], 1u);
        if ((b >> 21) == target) atomicAdd(&h[(b >> 10) & 0x7FFu], 1u);
        if ((c >> 21) == target) atomicAdd(&h[(c >> 10) & 0x7FFu], 1u);
        if ((d >> 21) == target) atomicAdd(&h[(d >> 10) & 0x7FFu], 1u);
    }
    if (blockIdx.y == 0 && tid < DETTOT - 4 * NVEC) {
        unsigned u = __float_as_uint(fabsf(dp[4 * NVEC + tid]));
        if ((u >> 21) == target) atomicAdd(&h[(u >> 10) & 0x7FFu], 1u);
    }
    __syncthreads();
    for (int i = tid; i < 2048; i += 256)
        if (h[i]) atomicAdd(&hist[m * 2048 + i], h[i]);
}

__global__ __launch_bounds__(256) void k_hist3(const float* __restrict__ det,
                                               const int* __restrict__ selBin1,
                                               const int* __restrict__ selBin2,
                                               unsigned* __restrict__ hist) {
    __shared__ unsigned h[1024];
    const int tid = threadIdx.x, m = blockIdx.x;
    const unsigned target = ((unsigned)selBin1[m] << 11) | (unsigned)selBin2[m];
    for (int i = tid; i < 1024; i += 256) h[i] = 0u;
    __syncthreads();
    const float* dp = det + (size_t)m * DETSTRIDE;
    const float4* dp4 = (const float4*)dp;
    const int stride = gridDim.y * 256;
    for (int v = blockIdx.y * 256 + tid; v < NVEC; v += stride) {
        float4 f = dp4[v];
        unsigned a = __float_as_uint(fabsf(f.x));
        unsigned b = __float_as_uint(fabsf(f.y));
        unsigned c = __float_as_uint(fabsf(f.z));
        unsigned d = __float_as_uint(fabsf(f.w));
        if ((a >> 10) == target) atomicAdd(&h[a & 0x3FFu], 1u);
        if ((b >> 10) == target) atomicAdd(&h[b & 0x3FFu], 1u);
        if ((c >> 10) == target) atomicAdd(&h[c & 0x3FFu], 1u);
        if ((d >> 10) == target) atomicAdd(&h[d & 0x3FFu], 1u);
    }
    if (blockIdx.y == 0 && tid < DETTOT - 4 * NVEC) {
        unsigned u = __float_as_uint(fabsf(dp[4 * NVEC + tid]));
        if ((u >> 10) == target) atomicAdd(&h[u & 0x3FFu], 1u);
    }
    __syncthreads();
    for (int i = tid; i < 1024; i += 256)
        if (h[i]) atomicAdd(&hist[m * 1024 + i], h[i]);
}

// Cooperative select: find bin of LDS histogram (nb multiple of 256) containing `rank`
__device__ int histSelect(unsigned* hist, int nb, unsigned rank, unsigned* rem) {
    __shared__ unsigned ps[256];
    __shared__ int s_bin;
    __shared__ unsigned s_rem;
    const int tid = threadIdx.x;
    if (tid == 0) { s_bin = 0; s_rem = 0; }      // deterministic fallback
    const int per = nb >> 8;
    unsigned s = 0;
    for (int i = 0; i < per; ++i) s += hist[tid * per + i];
    ps[tid] = s;
    __syncthreads();
    for (int off = 1; off < 256; off <<= 1) {
        unsigned v = ps[tid];
        unsigned add = (tid >= off) ? ps[tid - off] : 0u;
        __syncthreads();
        ps[tid] = v + add;
        __syncthreads();
    }
    unsigned incl = ps[tid], excl = incl - s;
    if (rank >= excl && rank < incl) {
        unsigned cum = excl;
        for (int i = 0; i < per; ++i) {
            unsigned c = hist[tid * per + i];
            if (cum + c > rank) { s_bin = tid * per + i; s_rem = rank - cum; break; }
            cum += c;
        }
    }
    __syncthreads();
    int rbin = s_bin;
    unsigned rr = s_rem;
    __syncthreads();   // protect shared reuse across calls
    *rem = rr;
    return rbin;
}

__global__ __launch_bounds__(256) void k_sel2048(const unsigned* __restrict__ hist,
                                                 const unsigned* __restrict__ rankIn, // null => KRANK
                                                 int* __restrict__ selBin,
                                                 unsigned* __restrict__ rankOut) {
    __shared__ unsigned h[2048];
    const int m = blockIdx.x, tid = threadIdx.x;
    for (int i = tid; i < 2048; i += 256) h[i] = hist[m * 2048 + i];
    __syncthreads();
    unsigned rank = rankIn ? rankIn[m] : KRANK;
    unsigned rem;
    int bin = histSelect(h, 2048, rank, &rem);
    if (tid == 0) { selBin[m] = bin; rankOut[m] = rem; }
}

__global__ __launch_bounds__(256) void k_sel3(const unsigned* __restrict__ hist,
                                              const unsigned* __restrict__ rankIn,
                                              const int* __restrict__ selBin1,
                                              const int* __restrict__ selBin2,
                                              float* __restrict__ tval) {
    __shared__ unsigned h[1024];
    const int m = blockIdx.x, tid = threadIdx.x;
    for (int i = tid; i < 1024; i += 256) h[i] = hist[m * 1024 + i];
    __syncthreads();
    unsigned rem;
    int low = histSelect(h, 1024, rankIn[m], &rem);
    if (tid == 0) {
        unsigned bits = ((unsigned)selBin1[m] << 21) | ((unsigned)selBin2[m] << 10) | (unsigned)low;
        double med = (double)__uint_as_float(bits);
        // t = median/0.6745 * sqrt(2*ln(512*512))
        tval[m] = (float)(med / 0.6745 * 4.995327667046959);
    }
}

// ---------------- Fused inverse: soft-threshold + column IDWT + row IDWT ------
// One block per (m, 64-w tile, 32-t tile). Stages 23x39 of 4 subbands (thresholded),
// computes 32x39 rl/rh in LDS, then row-IDWT to a 32x64 output tile (NHWC).
// (round-0 version — the register-blocked v2 variant regressed ~45 us)
__global__ __launch_bounds__(256) void k_inv(const float* __restrict__ ll,
                                             const float* __restrict__ det,
                                             const float* __restrict__ tval,
                                             float* __restrict__ out) {
    __shared__ float sLL[23 * 40], sLH[23 * 40], sHL[23 * 40], sHH[23 * 40];
    __shared__ float sRL[32 * 40], sRH[32 * 40];
    const int m  = blockIdx.x;                   // channels adjacent in dispatch
    const int w0 = blockIdx.y * 64;              // 8 tiles
    const int t0 = blockIdx.z * 32;              // 16 tiles
    const int b = m / 3, c = m - 3 * (m / 3);
    const int tid = threadIdx.x;
    const float thr = tval[m];
    const int jW0 = w0 >> 1, s0 = t0 >> 1;
    const float* llp = ll + (size_t)m * DETPER;
    const float* dp  = det + (size_t)m * DETSTRIDE;
    for (int l = tid; l < 23 * 39; l += 256) {
        int rr = l / 39, cc = l - rr * 39;
        size_t o = (size_t)(s0 + rr) * NW_ + (jW0 + cc);
        int li = rr * 40 + cc;
        sLL[li] = llp[o];
        sLH[li] = softthr(dp[o], thr);
        sHL[li] = softthr(dp[DETPER + o], thr);
        sHH[li] = softthr(dp[2 * DETPER + o], thr);
    }
    __syncthreads();
    // column IDWT: rl/rh rows t0..t0+31 at 39 jW cols
    for (int l = tid; l < 32 * 39; l += 256) {
        int tr = l / 39, cc = l - tr * 39;
        int srow = tr >> 1, r = tr & 1;
        float aL = 0.f, aH = 0.f;
#pragma unroll
        for (int a = 0; a < 8; ++a) {
            int li = (srow + 7 - a) * 40 + cc;
            float wl = RLO[2 * a + r], wh = RHI[2 * a + r];
            aL = fmaf(sLL[li], wl, fmaf(sLH[li], wh, aL));
            aH = fmaf(sHL[li], wl, fmaf(sHH[li], wh, aH));
        }
        sRL[tr * 40 + cc] = aL;
        sRH[tr * 40 + cc] = aH;
    }
    __syncthreads();
    // row IDWT + NHWC store
    for (int l = tid; l < 32 * 64; l += 256) {
        int tr = l >> 6, wloc = l & 63;
        int r = wloc & 1, jb = (wloc >> 1) + 7;  // local col index base, in [7,38]
        float acc = 0.f;
#pragma unroll
        for (int a = 0; a < 8; ++a) {
            int li = tr * 40 + jb - a;
            acc = fmaf(sRL[li], RLO[2 * a + r], fmaf(sRH[li], RHI[2 * a + r], acc));
        }
        out[((size_t)(b * H_ + (t0 + tr)) * W_ + (w0 + wloc)) * C_ + c] = acc;
    }
}

extern "C" void kernel_launch(void* const* d_in, const int* in_sizes, int n_in,
                              void* d_out, int out_size, void* d_ws, size_t ws_size,
                              hipStream_t stream) {
    const float* x = (const float*)d_in[0];
    float* out = (float*)d_out;

    char* ws = (char*)d_ws;
    float* ll  = (float*)ws; ws += (size_t)M_ * DETPER * 4;     // 26.56 MB
    float* det = (float*)ws; ws += (size_t)M_ * DETSTRIDE * 4;  // 79.68 MB  [m][{lh,hl,hh}][DETPER]
    unsigned* hist1 = (unsigned*)ws; ws += (size_t)M_ * 2048 * 4;
    unsigned* hist2 = (unsigned*)ws; ws += (size_t)M_ * 2048 * 4;
    unsigned* hist3 = (unsigned*)ws; ws += (size_t)M_ * 1024 * 4;
    int*      selBin1 = (int*)ws;      ws += M_ * 4;
    int*      selBin2 = (int*)ws;      ws += M_ * 4;
    unsigned* rank1   = (unsigned*)ws; ws += M_ * 4;
    unsigned* rank2   = (unsigned*)ws; ws += M_ * 4;
    float*    tval    = (float*)ws;    ws += M_ * 4;
    // total ws usage: ~108.2 MB

    const int histWords = M_ * (2048 + 2048 + 1024);            // 491,520
    k_zero   <<<dim3((histWords + 255) / 256), 256, 0, stream>>>(hist1, histWords);
    k_fwd    <<<dim3(M_, 5, 17),  256, 0, stream>>>(x, ll, det);
    k_hist1  <<<dim3(M_, 16),     256, 0, stream>>>(det, hist1);
    k_sel2048<<<dim3(M_),         256, 0, stream>>>(hist1, nullptr, selBin1, rank1);
    k_hist2  <<<dim3(M_, 16),     256, 0, stream>>>(det, selBin1, hist2);
    k_sel2048<<<dim3(M_),         256, 0, stream>>>(hist2, rank1, selBin2, rank2);
    k_hist3  <<<dim3(M_, 16),     256, 0, stream>>>(det, selBin1, selBin2, hist3);
    k_sel3   <<<dim3(M_),         256, 0, stream>>>(hist3, rank2, selBin1, selBin2, tval);
    k_inv    <<<dim3(M_, 8, 16),  256, 0, stream>>>(ll, det, tval, out);
}